// Round 12
// baseline (96.557 us; speedup 1.0000x reference)
//
#include <hip/hip_runtime.h>

// Problem constants
#define BATCH 16
#define CIN   64
#define H_    64
#define W_    64
#define IMG   (H_ * W_)      // 4096
#define OCH   128
#define NLEAF 16
#define NGATE 15
#define PH    32
#define PW    32

// LDS layout (floats). Total 19460 floats = 77,840 B -> 2 blocks/CU.
//   [0,1]  guard zeros (desc underflow target for ch=0,py=0,px=0, lane 0)
//   XS:    [64 ch][4 rows][66 cols]; cols 64,65 zero -> free column halos
//          (col -1 of row r aliases row r-1's zero pad; row stride 66);
//          staged x rows r0-1..r0+2, OOB rows zeroed
//   OPS:   128 ocs x 16 op bytes (argmax index per gate; byte 15 pad)
//   DS:    leaf descriptors, 128 x 16 ints: XSB + ch*264 + py*66 + px - 1
#define SROWS  4
#define RSTR   66
#define CHSTR  (SROWS * RSTR)           // 264
#define XSB    2
#define OPS_F  16900                    // 16B-aligned (16900*4 % 16 == 0)
#define DS_F   (OPS_F + OCH * 4)        // 17412 (16B-aligned)
#define SMEM_F (DS_F + OCH * NLEAF)     // 19460 floats

typedef float f2 __attribute__((ext_vector_type(2)));

__device__ __constant__ __align__(16) float OP2POLY[16][4] = {
    {0, 0, 0, 0}, {0, 0, 0, 1}, {0, 1, 0, -1}, {0, 1, 0, 0},
    {0, 0, 1, -1}, {0, 0, 1, 0}, {0, 1, 1, -2}, {0, 1, 1, -1},
    {1, -1, -1, 1}, {1, -1, -1, 2}, {1, 0, -1, 0}, {1, 0, -1, 1},
    {1, -1, 0, 0}, {1, -1, 0, 1}, {1, 0, 0, -1}, {1, 0, 0, 0}};

static __device__ __forceinline__ int rfl_i(int v) {
    return __builtin_amdgcn_readfirstlane(v);
}

// ---------------------------------------------------------------------------
// Single fused kernel, 2 blocks/CU. Block = (b, strip of 2 pre-pool rows);
// 512 threads = 8 waves; grid 512; XCD swizzle (XCD x -> batches 2x,2x+1).
// Phase 1: stage x rows r0-1..r0+2 (64 ch) into stride-66 LDS with zeroed
// pads (free halos; col pads folded into the staging loop as the 33rd
// float2); redundantly compute per-gate argmax op bytes (forward value of
// the straight-through w is exactly the one-hot argmax) and leaf
// descriptors into LDS. Phase 2: wave w -> ocs [16w,16w+16); lane = column.
// Per oc: op bytes via broadcast ds_read_b128 -> readfirstlane -> scalar
// OP2POLY lookup (K$-hot); descs as int4; base = desc + lane; the 2 rows
// per leaf via one ds_read2_b32 (offsets 0/66); 15-gate tree in packed f2;
// 2x2 noisy-or pool; even-lane store. Co-resident sibling block overlaps
// its VMEM staging with this block's LDS/VALU phase (the R12 point).
// ---------------------------------------------------------------------------
__global__ __launch_bounds__(512, 4) void logic_tree_fused(
    const float* __restrict__ x,        // (B, Cin, 64, 64)
    const float* __restrict__ weights,  // (OC, 15, 16)
    const int* __restrict__ ci,         // (OC, 16)
    const int* __restrict__ px,         // (OC, 16)
    const int* __restrict__ py,         // (OC, 16)
    float* __restrict__ out)            // (B, OC, 32, 32)
{
    __shared__ float smem[SMEM_F];
    int* smem_i = (int*)smem;
    unsigned char* smem_b = (unsigned char*)smem;

    const int blk = blockIdx.x;
    const int xcd = blk & 7;
    const int j   = blk >> 3;                 // 0..63
    const int b   = (xcd << 1) | (j >> 5);
    const int strip = j & 31;                 // pooled output row
    const int r0  = strip << 1;               // first pre-pool row
    const int tid = threadIdx.x;

    // ---- stage x rows r0-1..r0+2 (8448 float2 incl. col-pad pairs) ----
    const float2* xb2 =
        reinterpret_cast<const float2*>(x + (size_t)b * (CIN * IMG));
#pragma unroll
    for (int i = 0; i < 17; ++i) {
        int f = tid + i * 512;
        if (f < 8448) {
            int ch  = f / 132;               // 132 float2 per ch (4 rows x 33)
            int rem = f - ch * 132;
            int row = rem / 33;
            int c2  = rem - row * 33;        // 0..32; 32 = col pad (64,65)
            int gr  = r0 - 1 + row;
            float2 val = make_float2(0.f, 0.f);
            if (c2 < 32 && (unsigned)gr < (unsigned)H_)
                val = xb2[((ch << 6) | gr) * 32 + c2];
            *reinterpret_cast<float2*>(
                &smem[XSB + ch * CHSTR + row * RSTR + c2 * 2]) = val;
        }
    }
    if (tid < 2) smem[tid] = 0.0f;           // guard zeros

    // ---- per-gate argmax -> op byte (byte 15 of each oc zeroed) ----
#pragma unroll
    for (int i = 0; i < 4; ++i) {
        int t = tid + i * 512;               // < 2048; 1920 used
        if (t < OCH * NGATE) {
            const float4* wp4 = reinterpret_cast<const float4*>(weights + t * 16);
            const float4 a0 = wp4[0], a1 = wp4[1], a2 = wp4[2], a3 = wp4[3];
            const float wv[16] = {a0.x, a0.y, a0.z, a0.w, a1.x, a1.y, a1.z, a1.w,
                                  a2.x, a2.y, a2.z, a2.w, a3.x, a3.y, a3.z, a3.w};
            int best = 0;
            float bv = wv[0];
#pragma unroll
            for (int k = 1; k < 16; ++k)
                if (wv[k] > bv) { bv = wv[k]; best = k; }  // first-max (argmax)
            int oc = t / 15, g = t - oc * 15;
            smem_b[OPS_F * 4 + oc * 16 + g] = (unsigned char)best;
            if (g == 14) smem_b[OPS_F * 4 + oc * 16 + 15] = 0;
        }
    }
    // ---- leaf descriptors ----
#pragma unroll
    for (int i = 0; i < 4; ++i) {
        int t = tid + i * 512;               // < 2048
        smem_i[DS_F + t] = XSB + ci[t] * CHSTR + py[t] * RSTR + px[t] - 1;
    }
    __syncthreads();

    const int wave = tid >> 6;
    const int lane = tid & 63;

#pragma unroll 1
    for (int q = 0; q < 16; ++q) {
        const int oc = wave * 16 + q;

        // op bytes: one broadcast ds_read_b128 -> SGPRs
        const uint4 opsv = *reinterpret_cast<const uint4*>(&smem[OPS_F + oc * 4]);
        const unsigned ou[4] = {
            (unsigned)rfl_i((int)opsv.x), (unsigned)rfl_i((int)opsv.y),
            (unsigned)rfl_i((int)opsv.z), (unsigned)rfl_i((int)opsv.w)};

        // leaf descriptors (int4 LDS loads), base = desc + lane
        int base[NLEAF];
        const int4* D4 = reinterpret_cast<const int4*>(smem_i + DS_F + oc * NLEAF);
#pragma unroll
        for (int m = 0; m < 4; ++m) {
            const int4 d = D4[m];
            base[4 * m + 0] = d.x + lane;
            base[4 * m + 1] = d.y + lane;
            base[4 * m + 2] = d.z + lane;
            base[4 * m + 3] = d.w + lane;
        }

        // 2 pre-pool rows per leaf via one ds_read2_b32 (offsets 0/66)
        f2 v[NLEAF];
#pragma unroll
        for (int n = 0; n < NLEAF; ++n) {
            v[n].x = smem[base[n]];
            v[n].y = smem[base[n] + RSTR];
        }

        // 15-gate polynomial tree, packed f2; coeffs via K$-hot OP2POLY
        int go = 0;
#pragma unroll
        for (int lev = 8; lev >= 1; lev >>= 1) {
#pragma unroll
            for (int t = 0; t < lev; ++t) {
                const int g  = go + t;
                const int op = (int)((ou[g >> 2] >> ((g & 3) * 8)) & 255u);
                const float4 cc = reinterpret_cast<const float4*>(OP2POLY)[op];
                f2 a  = v[2 * t];
                f2 bb = v[2 * t + 1];
                v[t] = cc.x + cc.y * a + cc.z * bb + cc.w * (a * bb);
            }
            go += lev;
        }

        // 2x2 noisy-or pool -> one pooled row; even lanes store
        float p  = (1.0f - v[0].x) * (1.0f - v[0].y);   // row-pair product
        float pp = p * __shfl_xor(p, 1, 64);            // column-pair product
        if (!(lane & 1))
            out[(((size_t)b * OCH + oc) * PH + strip) * PW + (lane >> 1)] =
                1.0f - pp;
    }
}

extern "C" void kernel_launch(void* const* d_in, const int* in_sizes, int n_in,
                              void* d_out, int out_size, void* d_ws, size_t ws_size,
                              hipStream_t stream) {
    const float* x       = (const float*)d_in[0];
    const float* weights = (const float*)d_in[1];
    const int*   ci      = (const int*)d_in[2];
    const int*   px      = (const int*)d_in[3];
    const int*   py      = (const int*)d_in[4];
    float* out = (float*)d_out;
    (void)d_ws; (void)ws_size;

    logic_tree_fused<<<BATCH * 32, 512, 0, stream>>>(x, weights, ci, px, py, out);
}